// Round 9
// baseline (94.360 us; speedup 1.0000x reference)
//
#include <hip/hip_runtime.h>
#include <hip/hip_bf16.h>

#define B_    2
#define H_    16
#define HKV_  4
#define SQ_   1024
#define SP_   1024
#define SK_   2048
#define D_    128
#define QBLK  64
#define KVBLK 64
#define TILEB 32768       // ws tile: 16KB K + 16KB Vt (bf16, pre-swizzled LDS image)
#define NPAST 128         // 8 groups x 16 past tiles
#define NTILES 640        // + 32 heads x 16 new tiles

typedef __attribute__((ext_vector_type(8))) __bf16 bf16x8;
typedef __attribute__((ext_vector_type(4))) __bf16 bf16x4;
typedef __attribute__((ext_vector_type(4))) float  f32x4;

__device__ inline __bf16 f2bf(float f) { return (__bf16)f; }

__device__ inline void gl_lds16(const char* g, char* l) {
    __builtin_amdgcn_global_load_lds(
        (const __attribute__((address_space(1))) void*)g,
        (__attribute__((address_space(3))) void*)l, 16, 0, 0);
}

// ---- prep: present_key/value copy + bf16/swizzled tile build (once per KV tile) ----
__global__ __launch_bounds__(256)
void prep_kernel(const float* __restrict__ Kin, const float* __restrict__ Vin,
                 const float* __restrict__ PK,  const float* __restrict__ PV,
                 float* __restrict__ opk, float* __restrict__ opv, char* __restrict__ ws)
{
    __shared__ __align__(16) char Tl[TILEB];
    const int tid = threadIdx.x;
    const int id  = blockIdx.x;        // 0..639

    const float *ksrc, *vsrc;
    float *pkdst = nullptr, *pvdst = nullptr;
    size_t tidx;
    if (id < NPAST) {
        int grp = id & 7, kt = id >> 3;
        int s0 = kt * 64;
        ksrc = PK + (((size_t)grp)*SP_ + s0)*(size_t)D_;
        vsrc = PV + (((size_t)grp)*SP_ + s0)*(size_t)D_;
        pkdst = opk + (((size_t)grp)*SK_ + s0)*(size_t)D_;
        pvdst = opv + (((size_t)grp)*SK_ + s0)*(size_t)D_;
        tidx = (size_t)(grp*16 + kt);
    } else {
        int nid = id - NPAST;
        int h16 = nid >> 4;
        int ktp = nid & 15;
        int bb = h16 >> 4, hh = h16 & 15;
        int s0 = ktp * 64;
        ksrc = Kin + (((size_t)h16)*SQ_ + s0)*(size_t)D_;
        vsrc = Vin + (((size_t)h16)*SQ_ + s0)*(size_t)D_;
        if ((hh & 3) == 0) {
            int grp = bb*4 + (hh >> 2);
            pkdst = opk + (((size_t)grp)*SK_ + SP_ + s0)*(size_t)D_;
            pvdst = opv + (((size_t)grp)*SK_ + SP_ + s0)*(size_t)D_;
        }
        tidx = (size_t)(NPAST + nid);
    }

    #pragma unroll
    for (int i = 0; i < 4; ++i) {
        int idx = i*256 + tid, row = idx >> 4, c8 = idx & 15;
        f32x4 a0 = *(const f32x4*)(ksrc + row*D_ + c8*8);
        f32x4 a1 = *(const f32x4*)(ksrc + row*D_ + c8*8 + 4);
        if (pkdst) {
            *(f32x4*)(pkdst + row*D_ + c8*8)     = a0;
            *(f32x4*)(pkdst + row*D_ + c8*8 + 4) = a1;
        }
        bf16x8 f;
        #pragma unroll
        for (int j = 0; j < 4; ++j) { f[j] = f2bf(a0[j]); f[j+4] = f2bf(a1[j]); }
        int off = (row*256 + c8*16) ^ ((row & 7) << 4);
        *(bf16x8*)(Tl + off) = f;
    }
    #pragma unroll
    for (int i = 0; i < 2; ++i) {
        int blk = i*256 + tid, bk = blk & 15, bd = blk >> 4;
        f32x4 vr[4];
        #pragma unroll
        for (int kk = 0; kk < 4; ++kk)
            vr[kk] = *(const f32x4*)(vsrc + (4*bk+kk)*D_ + bd*4);
        #pragma unroll
        for (int j = 0; j < 4; ++j) {
            int d = 4*bd + j;
            bf16x4 t;
            t[0]=f2bf(vr[0][j]); t[1]=f2bf(vr[1][j]);
            t[2]=f2bf(vr[2][j]); t[3]=f2bf(vr[3][j]);
            int off = (d*128 + bk*8) ^ ((d & 7) << 4);
            *(bf16x4*)(Tl + 16384 + off) = t;
        }
    }
    if (pvdst) {
        #pragma unroll
        for (int i = 0; i < 4; ++i) {
            int idx = i*256 + tid, row = idx >> 4, c8 = idx & 15;
            *(f32x4*)(pvdst + row*D_ + c8*8)     = *(const f32x4*)(vsrc + row*D_ + c8*8);
            *(f32x4*)(pvdst + row*D_ + c8*8 + 4) = *(const f32x4*)(vsrc + row*D_ + c8*8 + 4);
        }
    }
    __syncthreads();
    char* dst = ws + tidx*TILEB;
    #pragma unroll
    for (int i = 0; i < 8; ++i) {
        int off = i*4096 + tid*16;
        *(f32x4*)(dst + off) = *(const f32x4*)(Tl + off);
    }
}

// ---- split-K attention: single-buffer 40KB LDS, 3-barrier rotating pipeline ----
// Race ledger: top vmcnt(4)+bar => all waves' K(kt) landed (V(kt) may fly).
// mid vmcnt(0)+bar => all waves' V(kt) landed AND all QK(kt) done => K-buf free,
// so STAGE_K(kt+1) after it is safe (issued before any new vmem => mid vmcnt(0)
// drains only V). end bar => all PV(kt) done => V-buf free => STAGE_V(kt+1).
__global__ __launch_bounds__(256, 2)
void attn_split_kernel(const float* __restrict__ Q, float* __restrict__ Out,
                       const char* __restrict__ ws,
                       float* __restrict__ wsO, float* __restrict__ wsML)
{
    __shared__ __align__(16) char Kb[16384];
    __shared__ __align__(16) char Vb[16384];
    __shared__ __align__(16) char Pl[8192];

    const int tid = threadIdx.x;
    const int id  = blockIdx.x;        // 0..1023
    // id%8 = XCD/KV-group; ids {r, r+256, r+512, r+768} (one CU under round-robin)
    // get {qt,15-qt}x{hf0,hf1}: per-CU work = 49 tile-units exactly.
    const int grp   = id & 7;          // b*4 + (h>>2)
    const int rest  = id >> 3;         // 0..127
    const int u     = rest & 31;
    const int v     = rest >> 5;       // 0..3
    const int qpair = u & 7;
    const int hi    = u >> 3;          // 0..3
    const int qt    = (v & 2) ? (15 - qpair) : qpair;
    const int hf    = v & 1;
    const int b     = grp >> 2;
    const int h     = (grp & 3)*4 + hi;
    const int h16   = b*16 + h;

    const int lane = tid & 63;
    const int w    = tid >> 6;
    const int lr   = lane & 15;
    const int lg   = lane >> 4;
    const int q0w  = qt * QBLK + w * 16;

    const int nt     = qt + 17;
    const int ch     = (qt + 18) >> 1;
    const int kt_beg = hf ? ch : 0;
    const int kt_end = hf ? nt : ch;

    const float scale_l2e = 0.08838834764831845f * 1.4426950408889634f; // 1/sqrt(128)*log2e

    const int boff = w*1024 + lane*16;
    auto tile_src = [&](int kt) {
        size_t t = (kt < 16) ? (size_t)(grp*16 + kt) : (size_t)(NPAST + h16*16 + (kt - 16));
        return ws + t*TILEB;
    };
    auto STAGE_K = [&](int kt) {
        const char* src = tile_src(kt);
        #pragma unroll
        for (int i = 0; i < 4; ++i) gl_lds16(src + i*4096 + boff, Kb + i*4096 + w*1024);
    };
    auto STAGE_V = [&](int kt) {
        const char* src = tile_src(kt);
        #pragma unroll
        for (int i = 0; i < 4; ++i) gl_lds16(src + 16384 + i*4096 + boff, Vb + i*4096 + w*1024);
    };

    // ---- Q loads first (compiler waits them for qf; DMAs stay outstanding) ----
    const float* qsrc = Q + (((size_t)h16)*SQ_ + q0w + lr)*(size_t)D_ + lg*8;
    f32x4 qa[4][2];
    #pragma unroll
    for (int c = 0; c < 4; ++c) {
        qa[c][0] = *(const f32x4*)(qsrc + c*32);
        qa[c][1] = *(const f32x4*)(qsrc + c*32 + 4);
    }
    STAGE_K(kt_beg);           // prologue: mimic steady state (K older than V)
    STAGE_V(kt_beg);

    bf16x8 qf[4];
    #pragma unroll
    for (int c = 0; c < 4; ++c) {
        bf16x8 f;
        #pragma unroll
        for (int j = 0; j < 4; ++j) {
            f[j]   = f2bf(qa[c][0][j] * scale_l2e);
            f[j+4] = f2bf(qa[c][1][j] * scale_l2e);
        }
        qf[c] = f;
    }

    f32x4 o[8];   // o[dt][r] = O[q = q0w+lr][d = dt*16 + lg*4 + r]
    #pragma unroll
    for (int i = 0; i < 8; ++i) o[i] = (f32x4){0.f,0.f,0.f,0.f};
    float m_r = -1e30f, l_r = 0.f;

    for (int kt = kt_beg; kt < kt_end; ++kt) {
        // ---- top: K(kt) ready across all waves ----
        asm volatile("s_waitcnt vmcnt(4)" ::: "memory");
        __builtin_amdgcn_sched_barrier(0);
        __builtin_amdgcn_s_barrier();
        __builtin_amdgcn_sched_barrier(0);

        // ---- QK^T swapped: lane holds k = n*16+lg*4+r, q = lr ----
        f32x4 s[4];
        #pragma unroll
        for (int n = 0; n < 4; ++n) s[n] = (f32x4){0.f,0.f,0.f,0.f};
        #pragma unroll
        for (int n = 0; n < 4; ++n) {
            #pragma unroll
            for (int c = 0; c < 4; ++c) {
                int off = ((n*16 + lr)*256 + c*64 + lg*16) ^ ((lr & 7) << 4);
                bf16x8 kf = *(const bf16x8*)(Kb + off);
                s[n] = __builtin_amdgcn_mfma_f32_16x16x32_bf16(kf, qf[c], s[n], 0, 0, 0);
            }
        }

        // ---- mid: V(kt) ready + K-buf free -> prefetch K(kt+1) ----
        asm volatile("s_waitcnt vmcnt(0)" ::: "memory");
        __builtin_amdgcn_sched_barrier(0);
        __builtin_amdgcn_s_barrier();
        __builtin_amdgcn_sched_barrier(0);
        if (kt + 1 < kt_end) STAGE_K(kt + 1);

        // ---- causal mask ----
        const int k0 = kt * KVBLK;
        float p[16];
        const bool needmask = (k0 + KVBLK - 1) > (q0w + SP_);
        if (needmask) {
            const int qv = q0w + lr + SP_;
            #pragma unroll
            for (int n = 0; n < 4; ++n)
                #pragma unroll
                for (int r = 0; r < 4; ++r) {
                    int kg = k0 + n*16 + lg*4 + r;
                    p[n*4+r] = (kg <= qv) ? s[n][r] : -1e30f;
                }
        } else {
            #pragma unroll
            for (int n = 0; n < 4; ++n)
                #pragma unroll
                for (int r = 0; r < 4; ++r) p[n*4+r] = s[n][r];
        }

        // ---- online softmax with defer-max (T13, THR=8, log2 domain) ----
        float mx = p[0];
        #pragma unroll
        for (int i = 1; i < 16; ++i) mx = fmaxf(mx, p[i]);
        mx = fmaxf(mx, __shfl_xor(mx, 16));
        mx = fmaxf(mx, __shfl_xor(mx, 32));
        if (!__all(mx <= m_r + 8.0f)) {
            float mnew  = fmaxf(m_r, mx);
            float alpha = exp2f(m_r - mnew);
            m_r = mnew;
            l_r *= alpha;
            #pragma unroll
            for (int dt = 0; dt < 8; ++dt) {
                o[dt][0] *= alpha; o[dt][1] *= alpha;
                o[dt][2] *= alpha; o[dt][3] *= alpha;
            }
        }
        float psum = 0.f;
        #pragma unroll
        for (int i = 0; i < 16; ++i) { p[i] = exp2f(p[i] - m_r); psum += p[i]; }
        psum += __shfl_xor(psum, 16);
        psum += __shfl_xor(psum, 32);
        l_r += psum;

        // ---- P -> per-wave LDS (own region; same-wave write->read) ----
        char* Pw = Pl + w*2048;
        #pragma unroll
        for (int n = 0; n < 4; ++n) {
            bf16x4 t;
            t[0]=f2bf(p[n*4+0]); t[1]=f2bf(p[n*4+1]);
            t[2]=f2bf(p[n*4+2]); t[3]=f2bf(p[n*4+3]);
            int off = (lr*128 + n*32 + lg*8) ^ ((lr & 7) << 4);
            *(bf16x4*)(Pw + off) = t;
        }

        // ---- PV swapped: O^T[d][q] += mfma(V, P) ----
        #pragma unroll
        for (int kk = 0; kk < 2; ++kk) {
            int poff = (lr*128 + kk*64 + lg*16) ^ ((lr & 7) << 4);
            bf16x8 pa = *(const bf16x8*)(Pw + poff);
            #pragma unroll
            for (int dt = 0; dt < 8; ++dt) {
                int voff = ((dt*16 + lr)*128 + kk*64 + lg*16) ^ ((lr & 7) << 4);
                bf16x8 vf = *(const bf16x8*)(Vb + voff);
                o[dt] = __builtin_amdgcn_mfma_f32_16x16x32_bf16(vf, pa, o[dt], 0, 0, 0);
            }
        }

        // ---- end: V-buf free -> prefetch V(kt+1) ----
        __builtin_amdgcn_sched_barrier(0);
        __builtin_amdgcn_s_barrier();
        __builtin_amdgcn_sched_barrier(0);
        if (kt + 1 < kt_end) STAGE_V(kt + 1);
    }

    // ---- epilogue: unnormalized partial -> ws ----
    const int slot = (h16*16 + qt)*2 + hf;          // 0..1023
    float* Oh = wsO + (size_t)slot*8192 + (size_t)(w*16 + lr)*128;
    #pragma unroll
    for (int dt = 0; dt < 8; ++dt)
        *(f32x4*)(Oh + dt*16 + lg*4) = o[dt];
    if (lg == 0) {
        wsML[(size_t)slot*128 + (w*16 + lr)*2]     = m_r;
        wsML[(size_t)slot*128 + (w*16 + lr)*2 + 1] = l_r;
    }
}

__global__ __launch_bounds__(256)
void combine_kernel(const float* __restrict__ wsO, const float* __restrict__ wsML,
                    float* __restrict__ Out)
{
    const int p   = blockIdx.x;            // (b*16+h)*16 + qt, 0..511 (64 rows each)
    const int tid = threadIdx.x;
    __shared__ float sml[64][2];
    if (tid < 64) {
        int s0 = (p*2    )*128 + tid*2;
        int s1 = (p*2 + 1)*128 + tid*2;
        float m1 = wsML[s0], l1 = wsML[s0+1];
        float m2 = wsML[s1], l2 = wsML[s1+1];
        float m  = fmaxf(m1, m2);
        float a1 = exp2f(m1 - m), a2 = exp2f(m2 - m);
        float inv = 1.0f / (l1*a1 + l2*a2);
        sml[tid][0] = a1 * inv;
        sml[tid][1] = a2 * inv;
    }
    __syncthreads();
    const float* O1 = wsO + (size_t)(p*2    )*8192;
    const float* O2 = wsO + (size_t)(p*2 + 1)*8192;
    float* dst = Out + (size_t)p*8192;
    #pragma unroll
    for (int i = 0; i < 8; ++i) {
        int v = i*256 + tid;               // f32x4 index, 0..2047
        int row = v >> 5;
        f32x4 x1 = *(const f32x4*)(O1 + (size_t)v*4);
        f32x4 x2 = *(const f32x4*)(O2 + (size_t)v*4);
        float a1 = sml[row][0], a2 = sml[row][1];
        f32x4 r;
        r[0]=x1[0]*a1+x2[0]*a2; r[1]=x1[1]*a1+x2[1]*a2;
        r[2]=x1[2]*a1+x2[2]*a2; r[3]=x1[3]*a1+x2[3]*a2;
        *(f32x4*)(dst + (size_t)v*4) = r;
    }
}

// ---- mid-tier: R8 lean kernel (no split), used when ws fits tiles only ----
__global__ __launch_bounds__(256, 2)
void attn_lean_kernel(const float* __restrict__ Q, float* __restrict__ Out,
                      const char* __restrict__ ws)
{
    __shared__ __align__(16) char Kb2[2][16384];
    __shared__ __align__(16) char Vb2[2][16384];
    __shared__ __align__(16) char Pl[8192];

    const int tid = threadIdx.x;
    const int id  = blockIdx.x;
    const int grp  = id & 7;
    const int rest = id >> 3;
    const int hi   = rest & 3;
    const int qt   = rest >> 2;
    const int b    = grp >> 2;
    const int h    = (grp & 3)*4 + hi;
    const int h16  = b*16 + h;

    const int lane = tid & 63;
    const int w    = tid >> 6;
    const int lr   = lane & 15;
    const int lg   = lane >> 4;
    const int q0w  = qt * QBLK + w * 16;
    const int nt   = qt + 17;

    const float scale_l2e = 0.08838834764831845f * 1.4426950408889634f;

    const int boff = w*1024 + lane*16;
    auto STAGE = [&](int buf, int kt) {
        size_t t = (kt < 16) ? (size_t)(grp*16 + kt) : (size_t)(NPAST + h16*16 + (kt - 16));
        const char* src = ws + t*TILEB;
        #pragma unroll
        for (int i = 0; i < 4; ++i) gl_lds16(src + i*4096 + boff,         Kb2[buf] + i*4096 + w*1024);
        #pragma unroll
        for (int i = 0; i < 4; ++i) gl_lds16(src + 16384 + i*4096 + boff, Vb2[buf] + i*4096 + w*1024);
    };

    STAGE(0, 0);

    bf16x8 qf[4];
    {
        const float* qsrc = Q + (((size_t)h16)*SQ_ + q0w + lr)*(size_t)D_ + lg*8;
        #pragma unroll
        for (int c = 0; c < 4; ++c) {
            f32x4 a0 = *(const f32x4*)(qsrc + c*32);
            f32x4 a1 = *(const f32x4*)(qsrc + c*32 + 4);
            bf16x8 f;
            #pragma unroll
            for (int j = 0; j < 4; ++j) {
                f[j]   = f2bf(a0[j] * scale_l2e);
                f[j+4] = f2bf(a1[j] * scale_l2e);
            }
            qf[c] = f;
        }
    }

    f32x4 o[8];
    #pragma unroll
    for (int i = 0; i < 8; ++i) o[i] = (f32x4){0.f,0.f,0.f,0.f};
    float m_r = -1e30f, l_r = 0.f;

    for (int kt = 0; kt < nt; ++kt) {
        const int cur = kt & 1;
        if (kt + 1 < nt) {
            STAGE(cur ^ 1, kt + 1);
            asm volatile("s_waitcnt vmcnt(8)" ::: "memory");
        } else {
            asm volatile("s_waitcnt vmcnt(0)" ::: "memory");
        }
        __builtin_amdgcn_sched_barrier(0);
        __builtin_amdgcn_s_barrier();
        __builtin_amdgcn_sched_barrier(0);

        const char* Kbp = Kb2[cur];
        const char* Vbp = Vb2[cur];

        f32x4 s[4];
        #pragma unroll
        for (int n = 0; n < 4; ++n) s[n] = (f32x4){0.f,0.f,0.f,0.f};
        #pragma unroll
        for (int n = 0; n < 4; ++n) {
            #pragma unroll
            for (int c = 0; c < 4; ++c) {
                int off = ((n*16 + lr)*256 + c*64 + lg*16) ^ ((lr & 7) << 4);
                bf16x8 kf = *(const bf16x8*)(Kbp + off);
                s[n] = __builtin_amdgcn_mfma_f32_16x16x32_bf16(kf, qf[c], s[n], 0, 0, 0);
            }
        }

        const int k0 = kt * KVBLK;
        float p[16];
        const bool needmask = (k0 + KVBLK - 1) > (q0w + SP_);
        if (needmask) {
            const int qv = q0w + lr + SP_;
            #pragma unroll
            for (int n = 0; n < 4; ++n)
                #pragma unroll
                for (int r = 0; r < 4; ++r) {
                    int kg = k0 + n*16 + lg*4 + r;
                    p[n*4+r] = (kg <= qv) ? s[n][r] : -1e30f;
                }
        } else {
            #pragma unroll
            for (int n = 0; n < 4; ++n)
                #pragma unroll
                for (int r = 0; r < 4; ++r) p[n*4+r] = s[n][r];
        }

        float mx = p[0];
        #pragma unroll
        for (int i = 1; i < 16; ++i) mx = fmaxf(mx, p[i]);
        mx = fmaxf(mx, __shfl_xor(mx, 16));
        mx = fmaxf(mx, __shfl_xor(mx, 32));
        if (!__all(mx <= m_r + 8.0f)) {
            float mnew  = fmaxf(m_r, mx);
            float alpha = exp2f(m_r - mnew);
            m_r = mnew;
            l_r *= alpha;
            #pragma unroll
            for (int dt = 0; dt < 8; ++dt) {
                o[dt][0] *= alpha; o[dt][1] *= alpha;
                o[dt][2] *= alpha; o[dt][3] *= alpha;
            }
        }
        float psum = 0.f;
        #pragma unroll
        for (int i = 0; i < 16; ++i) { p[i] = exp2f(p[i] - m_r); psum += p[i]; }
        psum += __shfl_xor(psum, 16);
        psum += __shfl_xor(psum, 32);
        l_r += psum;

        char* Pw = Pl + w*2048;
        #pragma unroll
        for (int n = 0; n < 4; ++n) {
            bf16x4 t;
            t[0]=f2bf(p[n*4+0]); t[1]=f2bf(p[n*4+1]);
            t[2]=f2bf(p[n*4+2]); t[3]=f2bf(p[n*4+3]);
            int off = (lr*128 + n*32 + lg*8) ^ ((lr & 7) << 4);
            *(bf16x4*)(Pw + off) = t;
        }

        #pragma unroll
        for (int kk = 0; kk < 2; ++kk) {
            int poff = (lr*128 + kk*64 + lg*16) ^ ((lr & 7) << 4);
            bf16x8 pa = *(const bf16x8*)(Pw + poff);
            #pragma unroll
            for (int dt = 0; dt < 8; ++dt) {
                int voff = ((dt*16 + lr)*128 + kk*64 + lg*16) ^ ((lr & 7) << 4);
                bf16x8 vf = *(const bf16x8*)(Vbp + voff);
                o[dt] = __builtin_amdgcn_mfma_f32_16x16x32_bf16(vf, pa, o[dt], 0, 0, 0);
            }
        }

        __builtin_amdgcn_sched_barrier(0);
        __builtin_amdgcn_s_barrier();
    }

    float inv = 1.0f / l_r;
    float* orow = Out + (((size_t)h16)*SQ_ + q0w + lr)*(size_t)D_;
    #pragma unroll
    for (int dt = 0; dt < 8; ++dt) {
        f32x4 st;
        st[0]=o[dt][0]*inv; st[1]=o[dt][1]*inv;
        st[2]=o[dt][2]*inv; st[3]=o[dt][3]*inv;
        *(f32x4*)(orow + dt*16 + lg*4) = st;
    }
}

// ======== final fallback (exact R4 path, used only if ws tiny) ========
__global__ __launch_bounds__(256, 2)
void attn_fallback_kernel(const float* __restrict__ Q, const float* __restrict__ Kin,
                          const float* __restrict__ Vin, const float* __restrict__ PK,
                          const float* __restrict__ PV, float* __restrict__ Out,
                          float* __restrict__ opk, float* __restrict__ opv)
{
    __shared__ __align__(16) __bf16 Klds[KVBLK * D_];
    __shared__ __align__(16) __bf16 Vlds[D_ * KVBLK];
    __shared__ __align__(16) __bf16 Plds[4 * 16 * KVBLK];

    const int tid = threadIdx.x;
    const int id  = blockIdx.x;

    if (id >= 512) {
        const int cid = id - 512;
        const int bgc = cid & 7;
        const int sub = cid >> 3;
        const int isV = sub >> 2;
        const int q4  = sub & 3;
        const int bb = bgc >> 2, g = bgc & 3;
        const float* past = isV ? PV : PK;
        const float* cur  = isV ? Vin : Kin;
        float* dst = isV ? opv : opk;
        const int base = bgc*65536 + q4*16384;
        #pragma unroll 4
        for (int i = 0; i < 64; ++i) {
            int id2 = base + i*256 + tid;
            int d4 = id2 & 31;
            int s  = (id2 >> 5) & (SK_-1);
            const float* srcp = (s < SP_)
                ? past + (((size_t)bgc)*SP_ + s)*(size_t)D_ + d4*4
                : cur  + (((size_t)(bb*H_ + 4*g))*SQ_ + (s - SP_))*(size_t)D_ + d4*4;
            float4 v = *(const float4*)srcp;
            *(float4*)(dst + (size_t)id2*4) = v;
        }
        return;
    }

    const int grp  = id & 7;
    const int rest = id >> 3;
    const int hi   = rest & 3;
    const int qt   = rest >> 2;
    const int b    = grp >> 2;
    const int h    = (grp & 3)*4 + hi;

    const int lane = tid & 63;
    const int w    = tid >> 6;
    const int lr   = lane & 15;
    const int lg   = lane >> 4;
    const int q0w  = qt * QBLK + w * 16;

    const float scale_l2e = 0.08838834764831845f * 1.4426950408889634f;

    bf16x8 qf[4];
    {
        const float* qsrc = Q + (((size_t)b*H_ + h)*SQ_ + q0w + lr)*(size_t)D_ + lg*8;
        #pragma unroll
        for (int c = 0; c < 4; ++c) {
            f32x4 a0 = *(const f32x4*)(qsrc + c*32);
            f32x4 a1 = *(const f32x4*)(qsrc + c*32 + 4);
            bf16x8 f;
            #pragma unroll
            for (int j = 0; j < 4; ++j) {
                f[j]   = f2bf(a0[j] * scale_l2e);
                f[j+4] = f2bf(a1[j] * scale_l2e);
            }
            qf[c] = f;
        }
    }

    f32x4 o[8];
    #pragma unroll
    for (int i = 0; i < 8; ++i) o[i] = (f32x4){0.f,0.f,0.f,0.f};
    float m_r = -1e30f, l_r = 0.f;

    const int nt = qt + 17;
    const size_t pk_base = (((size_t)b*HKV_ + (h>>2))*SP_)*(size_t)D_;
    const size_t kn_base = (((size_t)b*H_   + h     )*SQ_)*(size_t)D_;

    f32x4 kreg[4][2], vreg[2][4];
    auto loadKV = [&](const float* ks, const float* vs) {
        #pragma unroll
        for (int i = 0; i < 4; ++i) {
            int idx = i*256 + tid, row = idx >> 4, c8 = idx & 15;
            kreg[i][0] = *(const f32x4*)(ks + row*D_ + c8*8);
            kreg[i][1] = *(const f32x4*)(ks + row*D_ + c8*8 + 4);
        }
        #pragma unroll
        for (int i = 0; i < 2; ++i) {
            int blk = i*256 + tid, bk = blk & 15, bd = blk >> 4;
            #pragma unroll
            for (int kk = 0; kk < 4; ++kk)
                vreg[i][kk] = *(const f32x4*)(vs + (4*bk+kk)*D_ + bd*4);
        }
    };

    loadKV(PK + pk_base, PV + pk_base);

    for (int kt = 0; kt < nt; ++kt) {
        const int k0 = kt * KVBLK;
        __syncthreads();
        #pragma unroll
        for (int i = 0; i < 4; ++i) {
            int idx = i*256 + tid, row = idx >> 4, c8 = idx & 15;
            bf16x8 f;
            #pragma unroll
            for (int j = 0; j < 4; ++j) {
                f[j]   = f2bf(kreg[i][0][j]);
                f[j+4] = f2bf(kreg[i][1][j]);
            }
            int off = (row*256 + c8*16) ^ ((row & 7) << 4);
            *(bf16x8*)((char*)Klds + off) = f;
        }
        #pragma unroll
        for (int i = 0; i < 2; ++i) {
            int blk = i*256 + tid, bk = blk & 15, bd = blk >> 4;
            #pragma unroll
            for (int j = 0; j < 4; ++j) {
                int d = 4*bd + j;
                bf16x4 t;
                t[0]=f2bf(vreg[i][0][j]); t[1]=f2bf(vreg[i][1][j]);
                t[2]=f2bf(vreg[i][2][j]); t[3]=f2bf(vreg[i][3][j]);
                int off = (d*128 + bk*8) ^ ((d & 7) << 4);
                *(bf16x4*)((char*)Vlds + off) = t;
            }
        }
        __syncthreads();

        if (kt + 1 < nt) {
            const int k1 = k0 + KVBLK;
            const float* ks = (k1 < SP_) ? PK + pk_base + (size_t)k1*D_
                                         : Kin + kn_base + (size_t)(k1 - SP_)*D_;
            const float* vs = (k1 < SP_) ? PV + pk_base + (size_t)k1*D_
                                         : Vin + kn_base + (size_t)(k1 - SP_)*D_;
            loadKV(ks, vs);
        }

        f32x4 s[4];
        #pragma unroll
        for (int n = 0; n < 4; ++n) s[n] = (f32x4){0.f,0.f,0.f,0.f};
        #pragma unroll
        for (int n = 0; n < 4; ++n) {
            #pragma unroll
            for (int c = 0; c < 4; ++c) {
                int off = ((n*16 + lr)*256 + c*64 + lg*16) ^ ((lr & 7) << 4);
                bf16x8 kf = *(const bf16x8*)((char*)Klds + off);
                s[n] = __builtin_amdgcn_mfma_f32_16x16x32_bf16(kf, qf[c], s[n], 0, 0, 0);
            }
        }

        float p[16];
        const bool needmask = (k0 + KVBLK - 1) > (q0w + SP_);
        if (needmask) {
            const int qv = q0w + lr + SP_;
            #pragma unroll
            for (int n = 0; n < 4; ++n)
                #pragma unroll
                for (int r = 0; r < 4; ++r) {
                    int kg = k0 + n*16 + lg*4 + r;
                    p[n*4+r] = (kg <= qv) ? s[n][r] : -1e30f;
                }
        } else {
            #pragma unroll
            for (int n = 0; n < 4; ++n)
                #pragma unroll
                for (int r = 0; r < 4; ++r) p[n*4+r] = s[n][r];
        }

        float mx = p[0];
        #pragma unroll
        for (int i = 1; i < 16; ++i) mx = fmaxf(mx, p[i]);
        mx = fmaxf(mx, __shfl_xor(mx, 16));
        mx = fmaxf(mx, __shfl_xor(mx, 32));
        if (!__all(mx <= m_r + 8.0f)) {
            float mnew  = fmaxf(m_r, mx);
            float alpha = exp2f(m_r - mnew);
            m_r = mnew;
            l_r *= alpha;
            #pragma unroll
            for (int dt = 0; dt < 8; ++dt) {
                o[dt][0] *= alpha; o[dt][1] *= alpha;
                o[dt][2] *= alpha; o[dt][3] *= alpha;
            }
        }
        float psum = 0.f;
        #pragma unroll
        for (int i = 0; i < 16; ++i) { p[i] = exp2f(p[i] - m_r); psum += p[i]; }
        psum += __shfl_xor(psum, 16);
        psum += __shfl_xor(psum, 32);
        l_r += psum;

        char* Pw = (char*)Plds + w*2048;
        #pragma unroll
        for (int n = 0; n < 4; ++n) {
            bf16x4 t;
            t[0]=f2bf(p[n*4+0]); t[1]=f2bf(p[n*4+1]);
            t[2]=f2bf(p[n*4+2]); t[3]=f2bf(p[n*4+3]);
            int off = (lr*128 + n*32 + lg*8) ^ ((lr & 7) << 4);
            *(bf16x4*)(Pw + off) = t;
        }

        #pragma unroll
        for (int kk = 0; kk < 2; ++kk) {
            int poff = (lr*128 + kk*64 + lg*16) ^ ((lr & 7) << 4);
            bf16x8 pa = *(const bf16x8*)(Pw + poff);
            #pragma unroll
            for (int dt = 0; dt < 8; ++dt) {
                int voff = ((dt*16 + lr)*128 + kk*64 + lg*16) ^ ((lr & 7) << 4);
                bf16x8 vf = *(const bf16x8*)((char*)Vlds + voff);
                o[dt] = __builtin_amdgcn_mfma_f32_16x16x32_bf16(vf, pa, o[dt], 0, 0, 0);
            }
        }
    }

    float inv = 1.0f / l_r;
    float* orow = Out + (((size_t)b*H_ + h)*SQ_ + q0w + lr)*(size_t)D_;
    #pragma unroll
    for (int dt = 0; dt < 8; ++dt) {
        f32x4 st;
        st[0]=o[dt][0]*inv; st[1]=o[dt][1]*inv;
        st[2]=o[dt][2]*inv; st[3]=o[dt][3]*inv;
        *(f32x4*)(orow + dt*16 + lg*4) = st;
    }
}

extern "C" void kernel_launch(void* const* d_in, const int* in_sizes, int n_in,
                              void* d_out, int out_size, void* d_ws, size_t ws_size,
                              hipStream_t stream) {
    const float* Q   = (const float*)d_in[0];
    const float* K   = (const float*)d_in[1];
    const float* V   = (const float*)d_in[2];
    const float* PK  = (const float*)d_in[3];
    const float* PV  = (const float*)d_in[4];
    float* out = (float*)d_out;
    float* opk = out + (size_t)B_*H_*SQ_*D_;
    float* opv = opk + (size_t)B_*HKV_*SK_*D_;

    const size_t TILES_B = (size_t)NTILES * TILEB;                 // 20 MB
    const size_t SPLIT_B = TILES_B + (size_t)1024*8192*4 + (size_t)1024*128*4; // ~52.5 MB
    if (ws_size >= SPLIT_B) {
        char*  ws   = (char*)d_ws;
        float* wsO  = (float*)(ws + TILES_B);
        float* wsML = wsO + (size_t)1024*8192;
        prep_kernel<<<NTILES, 256, 0, stream>>>(K, V, PK, PV, opk, opv, ws);
        attn_split_kernel<<<1024, 256, 0, stream>>>(Q, out, ws, wsO, wsML);
        combine_kernel<<<512, 256, 0, stream>>>(wsO, wsML, out);
    } else if (ws_size >= TILES_B) {
        char* ws = (char*)d_ws;
        prep_kernel<<<NTILES, 256, 0, stream>>>(K, V, PK, PV, opk, opv, ws);
        attn_lean_kernel<<<512, 256, 0, stream>>>(Q, out, ws);
    } else {
        attn_fallback_kernel<<<576, 256, 0, stream>>>(Q, K, V, PK, PV, out, opk, opv);
    }
}

// Round 12
// 82.762 us; speedup vs baseline: 1.1401x; 1.1401x over previous
//
#include <hip/hip_runtime.h>
#include <hip/hip_bf16.h>

#define B_    2
#define H_    16
#define HKV_  4
#define SQ_   1024
#define SP_   1024
#define SK_   2048
#define D_    128
#define KVBLK 64
#define TILEB 32768       // ws tile: 16KB K + 16KB Vt (bf16, pre-swizzled LDS image)
#define NPAST 128         // 8 groups x 16 past tiles
#define NTILES 640        // + 32 heads x 16 new tiles

typedef __attribute__((ext_vector_type(8)))  __bf16 bf16x8;
typedef __attribute__((ext_vector_type(4)))  __bf16 bf16x4;
typedef __attribute__((ext_vector_type(4)))  float  f32x4;
typedef __attribute__((ext_vector_type(16))) float  f32x16;

__device__ inline __bf16 f2bf(float f) { return (__bf16)f; }

__device__ inline void gl_lds16(const char* g, char* l) {
    __builtin_amdgcn_global_load_lds(
        (const __attribute__((address_space(1))) void*)g,
        (__attribute__((address_space(3))) void*)l, 16, 0, 0);
}

// ---- prep: present copy + bf16 swizzled tile build ----
// K tile image: 64 rows x 256B, byte = row*256 + (colbyte ^ ((row&15)<<4))
// Vt tile image: 64 rows x 256B; row r holds V^T[d=r][k 0..63] in bytes 0..127
//                and V^T[d=r+64][k] in bytes 128..255; same XOR swizzle.
__global__ __launch_bounds__(256)
void prep_kernel(const float* __restrict__ Kin, const float* __restrict__ Vin,
                 const float* __restrict__ PK,  const float* __restrict__ PV,
                 float* __restrict__ opk, float* __restrict__ opv, char* __restrict__ ws)
{
    __shared__ __align__(16) char Tl[TILEB];
    const int tid = threadIdx.x;
    const int id  = blockIdx.x;        // 0..639

    const float *ksrc, *vsrc;
    float *pkdst = nullptr, *pvdst = nullptr;
    size_t tidx;
    if (id < NPAST) {
        int grp = id & 7, kt = id >> 3;
        int s0 = kt * 64;
        ksrc = PK + (((size_t)grp)*SP_ + s0)*(size_t)D_;
        vsrc = PV + (((size_t)grp)*SP_ + s0)*(size_t)D_;
        pkdst = opk + (((size_t)grp)*SK_ + s0)*(size_t)D_;
        pvdst = opv + (((size_t)grp)*SK_ + s0)*(size_t)D_;
        tidx = (size_t)(grp*16 + kt);
    } else {
        int nid = id - NPAST;
        int h16 = nid >> 4;
        int ktp = nid & 15;
        int bb = h16 >> 4, hh = h16 & 15;
        int s0 = ktp * 64;
        ksrc = Kin + (((size_t)h16)*SQ_ + s0)*(size_t)D_;
        vsrc = Vin + (((size_t)h16)*SQ_ + s0)*(size_t)D_;
        if ((hh & 3) == 0) {
            int grp = bb*4 + (hh >> 2);
            pkdst = opk + (((size_t)grp)*SK_ + SP_ + s0)*(size_t)D_;
            pvdst = opv + (((size_t)grp)*SK_ + SP_ + s0)*(size_t)D_;
        }
        tidx = (size_t)(NPAST + nid);
    }

    // K rows: coalesced read -> present copy + bf16 swizzled stage
    #pragma unroll
    for (int i = 0; i < 4; ++i) {
        int idx = i*256 + tid, row = idx >> 4, c8 = idx & 15;
        f32x4 a0 = *(const f32x4*)(ksrc + row*D_ + c8*8);
        f32x4 a1 = *(const f32x4*)(ksrc + row*D_ + c8*8 + 4);
        if (pkdst) {
            *(f32x4*)(pkdst + row*D_ + c8*8)     = a0;
            *(f32x4*)(pkdst + row*D_ + c8*8 + 4) = a1;
        }
        bf16x8 f;
        #pragma unroll
        for (int j = 0; j < 4; ++j) { f[j] = f2bf(a0[j]); f[j+4] = f2bf(a1[j]); }
        int off = row*256 + ((c8*16) ^ ((row & 15) << 4));
        *(bf16x8*)(Tl + off) = f;
    }
    // V transpose-stage into Vt image [16K..32K)
    #pragma unroll
    for (int i = 0; i < 2; ++i) {
        int blk = i*256 + tid, bk = blk & 15, bd = blk >> 4;   // bk: k-quad, bd: d-quad
        f32x4 vr[4];
        #pragma unroll
        for (int kk = 0; kk < 4; ++kk)
            vr[kk] = *(const f32x4*)(vsrc + (4*bk+kk)*D_ + bd*4);
        #pragma unroll
        for (int j = 0; j < 4; ++j) {
            int d = 4*bd + j;
            int r = d & 63, half = d >> 6;
            bf16x4 t;
            t[0]=f2bf(vr[0][j]); t[1]=f2bf(vr[1][j]);
            t[2]=f2bf(vr[2][j]); t[3]=f2bf(vr[3][j]);
            int off = r*256 + ((half*128 + 8*bk) ^ ((r & 15) << 4));
            *(bf16x4*)(Tl + 16384 + off) = t;
        }
    }
    if (pvdst) {
        #pragma unroll
        for (int i = 0; i < 4; ++i) {
            int idx = i*256 + tid, row = idx >> 4, c8 = idx & 15;
            *(f32x4*)(pvdst + row*D_ + c8*8)     = *(const f32x4*)(vsrc + row*D_ + c8*8);
            *(f32x4*)(pvdst + row*D_ + c8*8 + 4) = *(const f32x4*)(vsrc + row*D_ + c8*8 + 4);
        }
    }
    __syncthreads();
    char* dst = ws + tidx*TILEB;
    #pragma unroll
    for (int i = 0; i < 8; ++i) {
        int off = i*4096 + tid*16;
        *(f32x4*)(dst + off) = *(const f32x4*)(Tl + off);
    }
}

// ---- 32x32 MFMA attention, split-K x2, LDS P-bounce, dbuf DMA (R8 ledger) ----
// FIX vs R10/R11: buffer parity is relative to kt_beg (prologue stages buf 0);
// kt&1 read uninitialized LDS for odd kt_beg -> NaN.
__global__ __launch_bounds__(256, 2)
void attn32_kernel(const float* __restrict__ Q, const char* __restrict__ ws,
                   float* __restrict__ wsO, float* __restrict__ wsML)
{
    __shared__ __align__(16) char Kb2[2][16384];
    __shared__ __align__(16) char Vb2[2][16384];
    __shared__ __align__(16) char Pl[16384];   // 4 waves x 32 q-rows x 128B

    const int tid = threadIdx.x;
    const int id  = blockIdx.x;        // 0..511
    const int grp  = id & 7;           // b*4 + (h>>2): XCD-aligned KV group
    const int rest = id >> 3;          // 0..63
    const int hi4  = rest & 3;
    const int qt   = 7 - ((rest >> 2) & 7);   // longest first
    const int hf   = rest >> 5;
    const int b    = grp >> 2;
    const int h    = (grp & 3)*4 + hi4;
    const int h16  = b*16 + h;

    const int lane = tid & 63;
    const int w    = tid >> 6;         // 0..3, wave owns q rows [w*32, w*32+32)
    const int l31  = lane & 31;
    const int hi   = lane >> 5;
    const int swzm = (l31 & 15) << 4;
    const int q0w  = qt*128 + w*32;

    const int nt     = 2*qt + 18;
    const int ch     = qt + 9;
    const int kt_beg = hf ? ch : 0;
    const int kt_end = hf ? nt : ch;

    const float scale_l2e = 0.08838834764831845f * 1.4426950408889634f; // 1/sqrt(128)*log2e

    const int boff = w*1024 + lane*16;
    auto STAGE = [&](int buf, int kt) {
        size_t t = (kt < 16) ? (size_t)(grp*16 + kt) : (size_t)(NPAST + h16*16 + (kt - 16));
        const char* src = ws + t*TILEB;
        char* kb = Kb2[buf];
        char* vb = Vb2[buf];
        #pragma unroll
        for (int i = 0; i < 4; ++i) gl_lds16(src + i*4096 + boff,         kb + i*4096 + w*1024);
        #pragma unroll
        for (int i = 0; i < 4; ++i) gl_lds16(src + 16384 + i*4096 + boff, vb + i*4096 + w*1024);
    };

    STAGE(0, kt_beg);   // DMA for first tile starts immediately (into buf 0)

    // ---- Q B-fragments (pre-scaled): lane q = q0w + l31, chunk c: d = c*16 + hi*8 + j ----
    bf16x8 qf[8];
    {
        const float* qsrc = Q + ((size_t)h16*SQ_ + q0w + l31)*(size_t)D_;
        #pragma unroll
        for (int c = 0; c < 8; ++c) {
            f32x4 a0 = *(const f32x4*)(qsrc + c*16 + hi*8);
            f32x4 a1 = *(const f32x4*)(qsrc + c*16 + hi*8 + 4);
            bf16x8 f;
            #pragma unroll
            for (int j = 0; j < 4; ++j) {
                f[j]   = f2bf(a0[j] * scale_l2e);
                f[j+4] = f2bf(a1[j] * scale_l2e);
            }
            qf[c] = f;
        }
    }

    // O^T accumulators: o2[dblk], col=q=l31, row d = dblk*32 + (reg&3)+8*(reg>>2)+4*hi
    f32x16 o2[4];
    #pragma unroll
    for (int i = 0; i < 4; ++i)
        #pragma unroll
        for (int j = 0; j < 16; ++j) o2[i][j] = 0.f;
    float m_r = -1e30f, l_r = 0.f;

    char* Pw = Pl + w*4096;

    for (int kt = kt_beg; kt < kt_end; ++kt) {
        const int cur = (kt - kt_beg) & 1;   // parity relative to staged start (THE FIX)
        // issue next tile's DMA, wait ONLY for current tile (8 loads stay in flight)
        if (kt + 1 < kt_end) {
            STAGE(cur ^ 1, kt + 1);
            asm volatile("s_waitcnt vmcnt(8)" ::: "memory");
        } else {
            asm volatile("s_waitcnt vmcnt(0)" ::: "memory");
        }
        __builtin_amdgcn_sched_barrier(0);
        __builtin_amdgcn_s_barrier();        // all waves' tile-kt DMA published
        __builtin_amdgcn_sched_barrier(0);

        const char* Kbp = Kb2[cur];
        const char* Vbp = Vb2[cur];

        // ---- QK^T swapped 32x32x16: S^T block c2: rows k=c2*32+crow, cols q=l31 ----
        f32x16 s[2];
        #pragma unroll
        for (int c2 = 0; c2 < 2; ++c2)
            #pragma unroll
            for (int j = 0; j < 16; ++j) s[c2][j] = 0.f;
        #pragma unroll
        for (int c = 0; c < 8; ++c) {
            int cb = (c*32 + hi*16) ^ swzm;
            bf16x8 kf0 = *(const bf16x8*)(Kbp + l31*256 + cb);
            s[0] = __builtin_amdgcn_mfma_f32_32x32x16_bf16(kf0, qf[c], s[0], 0, 0, 0);
            bf16x8 kf1 = *(const bf16x8*)(Kbp + 8192 + l31*256 + cb);
            s[1] = __builtin_amdgcn_mfma_f32_32x32x16_bf16(kf1, qf[c], s[1], 0, 0, 0);
        }

        // ---- causal mask: general per-tile condition ----
        const int k0 = kt * KVBLK;
        if ((k0 + KVBLK - 1) > (q0w + SP_)) {
            const int qv = q0w + l31 + SP_;
            #pragma unroll
            for (int c2 = 0; c2 < 2; ++c2)
                #pragma unroll
                for (int r = 0; r < 16; ++r) {
                    int kg = k0 + 32*c2 + (r & 3) + 8*(r >> 2) + 4*hi;
                    if (kg > qv) s[c2][r] = -1e30f;
                }
        }

        // ---- online softmax (lane pair l, l+32 share q=l31): 1 shfl per reduce ----
        float mx = s[0][0];
        #pragma unroll
        for (int c2 = 0; c2 < 2; ++c2)
            #pragma unroll
            for (int r = 0; r < 16; ++r) mx = fmaxf(mx, s[c2][r]);
        mx = fmaxf(mx, __shfl_xor(mx, 32));
        if (!__all(mx <= m_r + 8.0f)) {          // defer-max (T13), log2 domain
            float mnew  = fmaxf(m_r, mx);
            float alpha = exp2f(m_r - mnew);
            m_r = mnew;
            l_r *= alpha;
            #pragma unroll
            for (int i = 0; i < 4; ++i)
                #pragma unroll
                for (int j = 0; j < 16; ++j) o2[i][j] *= alpha;
        }
        float psum = 0.f;
        #pragma unroll
        for (int c2 = 0; c2 < 2; ++c2)
            #pragma unroll
            for (int r = 0; r < 16; ++r) {
                float e = exp2f(s[c2][r] - m_r);
                s[c2][r] = e;
                psum += e;
            }
        psum += __shfl_xor(psum, 32);
        l_r += psum;

        // ---- P -> per-wave LDS bounce (C-layout in, B-layout out; swizzled) ----
        #pragma unroll
        for (int c2 = 0; c2 < 2; ++c2)
            #pragma unroll
            for (int rq = 0; rq < 4; ++rq) {
                bf16x4 t;
                t[0]=f2bf(s[c2][rq*4+0]); t[1]=f2bf(s[c2][rq*4+1]);
                t[2]=f2bf(s[c2][rq*4+2]); t[3]=f2bf(s[c2][rq*4+3]);
                int off = l31*128 + ((c2*64 + rq*16 + hi*8) ^ ((l31 & 7) << 4));
                *(bf16x4*)(Pw + off) = t;
            }

        // ---- PV: O^T[d][q] += mfma(Vt, P); B-frag read k = ks*16 + hi*8 + j ----
        #pragma unroll
        for (int ks = 0; ks < 4; ++ks) {
            int poff = l31*128 + ((ks*32 + hi*16) ^ ((l31 & 7) << 4));
            bf16x8 pf = *(const bf16x8*)(Pw + poff);
            #pragma unroll
            for (int dblk = 0; dblk < 4; ++dblk) {
                int r = (dblk & 1)*32 + l31;
                int off = r*256 + ((((dblk >> 1)*128) + ks*32 + hi*16) ^ swzm);
                bf16x8 vf = *(const bf16x8*)(Vbp + off);
                o2[dblk] = __builtin_amdgcn_mfma_f32_32x32x16_bf16(vf, pf, o2[dblk], 0, 0, 0);
            }
        }

        __builtin_amdgcn_sched_barrier(0);
        __builtin_amdgcn_s_barrier();        // compute(cur) done; next iter may DMA it
    }

    // ---- epilogue: unnormalized partial -> ws ----
    const int slot = (h16*8 + qt)*2 + hf;          // 0..511
    const int q    = w*32 + l31;
    float* Oh = wsO + (size_t)slot*16384 + (size_t)q*128;
    #pragma unroll
    for (int dblk = 0; dblk < 4; ++dblk)
        #pragma unroll
        for (int rg = 0; rg < 4; ++rg) {
            f32x4 st;
            st[0] = o2[dblk][rg*4+0]; st[1] = o2[dblk][rg*4+1];
            st[2] = o2[dblk][rg*4+2]; st[3] = o2[dblk][rg*4+3];
            *(f32x4*)(Oh + dblk*32 + rg*8 + hi*4) = st;
        }
    if (hi == 0) {
        wsML[(size_t)slot*256 + q*2]     = m_r;
        wsML[(size_t)slot*256 + q*2 + 1] = l_r;
    }
}

__global__ __launch_bounds__(256)
void combine_kernel(const float* __restrict__ wsO, const float* __restrict__ wsML,
                    float* __restrict__ Out)
{
    const int p   = blockIdx.x;            // (b*16+h)*8 + qt, 0..255 (128 q-rows each)
    const int tid = threadIdx.x;
    __shared__ float sml[128][2];
    if (tid < 128) {
        size_t s0 = (size_t)(p*2    )*256 + tid*2;
        size_t s1 = (size_t)(p*2 + 1)*256 + tid*2;
        float m1 = wsML[s0], l1 = wsML[s0+1];
        float m2 = wsML[s1], l2 = wsML[s1+1];
        float m  = fmaxf(m1, m2);
        float a1 = exp2f(m1 - m), a2 = exp2f(m2 - m);
        float inv = 1.0f / (l1*a1 + l2*a2);
        sml[tid][0] = a1 * inv;
        sml[tid][1] = a2 * inv;
    }
    __syncthreads();
    const float* O1 = wsO + (size_t)(p*2    )*16384;
    const float* O2 = wsO + (size_t)(p*2 + 1)*16384;
    float* dst = Out + (size_t)p*16384;
    #pragma unroll
    for (int i = 0; i < 16; ++i) {
        int v = i*256 + tid;               // f32x4 index, 0..4095
        int row = v >> 5;                  // 32 f32x4 per 128-wide row
        f32x4 x1 = *(const f32x4*)(O1 + (size_t)v*4);
        f32x4 x2 = *(const f32x4*)(O2 + (size_t)v*4);
        float a1 = sml[row][0], a2 = sml[row][1];
        f32x4 r;
        r[0]=x1[0]*a1+x2[0]*a2; r[1]=x1[1]*a1+x2[1]*a2;
        r[2]=x1[2]*a1+x2[2]*a2; r[3]=x1[3]*a1+x2[3]*a2;
        *(f32x4*)(dst + (size_t)v*4) = r;
    }
}

// ======== fallback (exact R4 path, used only if ws too small) ========
__global__ __launch_bounds__(256, 2)
void attn_fallback_kernel(const float* __restrict__ Q, const float* __restrict__ Kin,
                          const float* __restrict__ Vin, const float* __restrict__ PK,
                          const float* __restrict__ PV, float* __restrict__ Out,
                          float* __restrict__ opk, float* __restrict__ opv)
{
    __shared__ __align__(16) __bf16 Klds[KVBLK * D_];
    __shared__ __align__(16) __bf16 Vlds[D_ * KVBLK];
    __shared__ __align__(16) __bf16 Plds[4 * 16 * KVBLK];

    const int tid = threadIdx.x;
    const int id  = blockIdx.x;

    if (id >= 512) {
        const int cid = id - 512;
        const int bgc = cid & 7;
        const int sub = cid >> 3;
        const int isV = sub >> 2;
        const int q4  = sub & 3;
        const int bb = bgc >> 2, g = bgc & 3;
        const float* past = isV ? PV : PK;
        const float* cur  = isV ? Vin : Kin;
        float* dst = isV ? opv : opk;
        const int base = bgc*65536 + q4*16384;
        #pragma unroll 4
        for (int i = 0; i < 64; ++i) {
            int id2 = base + i*256 + tid;
            int d4 = id2 & 31;
            int s  = (id2 >> 5) & (SK_-1);
            const float* srcp = (s < SP_)
                ? past + (((size_t)bgc)*SP_ + s)*(size_t)D_ + d4*4
                : cur  + (((size_t)(bb*H_ + 4*g))*SQ_ + (s - SP_))*(size_t)D_ + d4*4;
            float4 v = *(const float4*)srcp;
            *(float4*)(dst + (size_t)id2*4) = v;
        }
        return;
    }

    const int grp  = id & 7;
    const int rest = id >> 3;
    const int hi   = rest & 3;
    const int qt   = rest >> 2;
    const int b    = grp >> 2;
    const int h    = (grp & 3)*4 + hi;

    const int lane = tid & 63;
    const int w    = tid >> 6;
    const int lr   = lane & 15;
    const int lg   = lane >> 4;
    const int q0w  = qt * 64 + w * 16;

    const float scale_l2e = 0.08838834764831845f * 1.4426950408889634f;

    bf16x8 qf[4];
    {
        const float* qsrc = Q + (((size_t)b*H_ + h)*SQ_ + q0w + lr)*(size_t)D_ + lg*8;
        #pragma unroll
        for (int c = 0; c < 4; ++c) {
            f32x4 a0 = *(const f32x4*)(qsrc + c*32);
            f32x4 a1 = *(const f32x4*)(qsrc + c*32 + 4);
            bf16x8 f;
            #pragma unroll
            for (int j = 0; j < 4; ++j) {
                f[j]   = f2bf(a0[j] * scale_l2e);
                f[j+4] = f2bf(a1[j] * scale_l2e);
            }
            qf[c] = f;
        }
    }

    f32x4 o[8];
    #pragma unroll
    for (int i = 0; i < 8; ++i) o[i] = (f32x4){0.f,0.f,0.f,0.f};
    float m_r = -1e30f, l_r = 0.f;

    const int nt = qt + 17;
    const size_t pk_base = (((size_t)b*HKV_ + (h>>2))*SP_)*(size_t)D_;
    const size_t kn_base = (((size_t)b*H_   + h     )*SQ_)*(size_t)D_;

    f32x4 kreg[4][2], vreg[2][4];
    auto loadKV = [&](const float* ks, const float* vs) {
        #pragma unroll
        for (int i = 0; i < 4; ++i) {
            int idx = i*256 + tid, row = idx >> 4, c8 = idx & 15;
            kreg[i][0] = *(const f32x4*)(ks + row*D_ + c8*8);
            kreg[i][1] = *(const f32x4*)(ks + row*D_ + c8*8 + 4);
        }
        #pragma unroll
        for (int i = 0; i < 2; ++i) {
            int blk = i*256 + tid, bk = blk & 15, bd = blk >> 4;
            #pragma unroll
            for (int kk = 0; kk < 4; ++kk)
                vreg[i][kk] = *(const f32x4*)(vs + (4*bk+kk)*D_ + bd*4);
        }
    };

    loadKV(PK + pk_base, PV + pk_base);

    for (int kt = 0; kt < nt; ++kt) {
        const int k0 = kt * KVBLK;
        __syncthreads();
        #pragma unroll
        for (int i = 0; i < 4; ++i) {
            int idx = i*256 + tid, row = idx >> 4, c8 = idx & 15;
            bf16x8 f;
            #pragma unroll
            for (int j = 0; j < 4; ++j) {
                f[j]   = f2bf(kreg[i][0][j]);
                f[j+4] = f2bf(kreg[i][1][j]);
            }
            int off = (row*256 + c8*16) ^ ((row & 7) << 4);
            *(bf16x8*)((char*)Klds + off) = f;
        }
        #pragma unroll
        for (int i = 0; i < 2; ++i) {
            int blk = i*256 + tid, bk = blk & 15, bd = blk >> 4;
            #pragma unroll
            for (int j = 0; j < 4; ++j) {
                int d = 4*bd + j;
                bf16x4 t;
                t[0]=f2bf(vreg[i][0][j]); t[1]=f2bf(vreg[i][1][j]);
                t[2]=f2bf(vreg[i][2][j]); t[3]=f2bf(vreg[i][3][j]);
                int off = (d*128 + bk*8) ^ ((d & 7) << 4);
                *(bf16x4*)((char*)Vlds + off) = t;
            }
        }
        __syncthreads();

        if (kt + 1 < nt) {
            const int k1 = k0 + KVBLK;
            const float* ks = (k1 < SP_) ? PK + pk_base + (size_t)k1*D_
                                         : Kin + kn_base + (size_t)(k1 - SP_)*D_;
            const float* vs = (k1 < SP_) ? PV + pk_base + (size_t)k1*D_
                                         : Vin + kn_base + (size_t)(k1 - SP_)*D_;
            loadKV(ks, vs);
        }

        f32x4 s[4];
        #pragma unroll
        for (int n = 0; n < 4; ++n) s[n] = (f32x4){0.f,0.f,0.f,0.f};
        #pragma unroll
        for (int n = 0; n < 4; ++n) {
            #pragma unroll
            for (int c = 0; c < 4; ++c) {
                int off = ((n*16 + lr)*256 + c*64 + lg*16) ^ ((lr & 7) << 4);
                bf16x8 kf = *(const bf16x8*)((char*)Klds + off);
                s[n] = __builtin_amdgcn_mfma_f32_16x16x32_bf16(kf, qf[c], s[n], 0, 0, 0);
            }
        }

        float p[16];
        const bool needmask = (k0 + KVBLK - 1) > (q0w + SP_);
        if (needmask) {
            const int qv = q0w + lr + SP_;
            #pragma unroll
            for (int n = 0; n < 4; ++n)
                #pragma unroll
                for (int r = 0; r < 4; ++r) {
                    int kg = k0 + n*16 + lg*4 + r;
                    p[n*4+r] = (kg <= qv) ? s[n][r] : -1e30f;
                }
        } else {
            #pragma unroll
            for (int n = 0; n < 4; ++n)
                #pragma unroll
                for (int r = 0; r < 4; ++r) p[n*4+r] = s[n][r];
        }

        float mx = p[0];
        #pragma unroll
        for (int i = 1; i < 16; ++i) mx = fmaxf(mx, p[i]);
        mx = fmaxf(mx, __shfl_xor(mx, 16));
        mx = fmaxf(mx, __shfl_xor(mx, 32));
        if (!__all(mx <= m_r + 8.0f)) {
            float mnew  = fmaxf(m_r, mx);
            float alpha = exp2f(m_r - mnew);
            m_r = mnew;
            l_r *= alpha;
            #pragma unroll
            for (int dt = 0; dt < 8; ++dt) {
                o[dt][0] *= alpha; o[dt][1] *= alpha;
                o[dt][2] *= alpha; o[dt][3] *= alpha;
            }
        }
        float psum = 0.f;
        #pragma unroll
        for (int i = 0; i < 16; ++i) { p[i] = exp2f(p[i] - m_r); psum += p[i]; }
        psum += __shfl_xor(psum, 16);
        psum += __shfl_xor(psum, 32);
        l_r += psum;

        char* Pw = (char*)Plds + w*2048;
        #pragma unroll
        for (int n = 0; n < 4; ++n) {
            bf16x4 t;
            t[0]=f2bf(p[n*4+0]); t[1]=f2bf(p[n*4+1]);
            t[2]=f2bf(p[n*4+2]); t[3]=f2bf(p[n*4+3]);
            int off = (lr*128 + n*32 + lg*8) ^ ((lr & 7) << 4);
            *(bf16x4*)(Pw + off) = t;
        }

        #pragma unroll
        for (int kk = 0; kk < 2; ++kk) {
            int poff = (lr*128 + kk*64 + lg*16) ^ ((lr & 7) << 4);
            bf16x8 pa = *(const bf16x8*)(Pw + poff);
            #pragma unroll
            for (int dt = 0; dt < 8; ++dt) {
                int voff = ((dt*16 + lr)*128 + kk*64 + lg*16) ^ ((lr & 7) << 4);
                bf16x8 vf = *(const bf16x8*)((char*)Vlds + voff);
                o[dt] = __builtin_amdgcn_mfma_f32_16x16x32_bf16(vf, pa, o[dt], 0, 0, 0);
            }
        }
    }

    float inv = 1.0f / l_r;
    float* orow = Out + (((size_t)b*H_ + h)*SQ_ + q0w + lr)*(size_t)D_;
    #pragma unroll
    for (int dt = 0; dt < 8; ++dt) {
        f32x4 st;
        st[0]=o[dt][0]*inv; st[1]=o[dt][1]*inv;
        st[2]=o[dt][2]*inv; st[3]=o[dt][3]*inv;
        *(f32x4*)(orow + dt*16 + lg*4) = st;
    }
}

extern "C" void kernel_launch(void* const* d_in, const int* in_sizes, int n_in,
                              void* d_out, int out_size, void* d_ws, size_t ws_size,
                              hipStream_t stream) {
    const float* Q   = (const float*)d_in[0];
    const float* K   = (const float*)d_in[1];
    const float* V   = (const float*)d_in[2];
    const float* PK  = (const float*)d_in[3];
    const float* PV  = (const float*)d_in[4];
    float* out = (float*)d_out;
    float* opk = out + (size_t)B_*H_*SQ_*D_;
    float* opv = opk + (size_t)B_*HKV_*SK_*D_;

    const size_t TILES_B = (size_t)NTILES * TILEB;                    // 20 MB
    const size_t NEED = TILES_B + (size_t)512*16384*4 + (size_t)512*256*4;  // ~55 MB
    if (ws_size >= NEED) {
        char*  ws   = (char*)d_ws;
        float* wsO  = (float*)(ws + TILES_B);
        float* wsML = wsO + (size_t)512*16384;
        prep_kernel<<<NTILES, 256, 0, stream>>>(K, V, PK, PV, opk, opv, ws);
        attn32_kernel<<<512, 256, 0, stream>>>(Q, ws, wsO, wsML);
        combine_kernel<<<256, 256, 0, stream>>>(wsO, wsML, out);
    } else {
        attn_fallback_kernel<<<576, 256, 0, stream>>>(Q, K, V, PK, PV, out, opk, opv);
    }
}